// Round 1
// baseline (864.037 us; speedup 1.0000x reference)
//
#include <hip/hip_runtime.h>
#include <math.h>

// Masked-argmax / masked-log-softmax CE+acc metric.
// logits: (N_LOOPS=4, B=4, L=256, V=50257) f32
// input_ids: (B, L) i32 ; ans_starts: (B,) i32 ; chain_targets: (B, N_LOOPS) i32
// outputs: 3 f32 scalars: avg_loss, avg_acc, final_loop_acc
//
// Structural fact: valid_tok has <=256 set bits per batch (256 input_ids).
// We compact the unique token ids and only touch those logits (~16 KB total
// instead of 823 MB). This round: single fused launch — the per-(n,b) row
// stats and the 48-value finalize run in ONE kernel via the last-block-done
// pattern (device-scope atomics + threadfence, correct across XCDs).

#define NL 4
#define BB 4
#define LL 256
#define VV 50257
#define VWORDS ((VV + 31) / 32)   // 1571
#define TPB 256
#define NBLK (NL * BB)            // 16

__global__ __launch_bounds__(TPB) void fused_metric_kernel(
    const float* __restrict__ logits,
    const int* __restrict__ input_ids,
    const int* __restrict__ ans_starts,
    const int* __restrict__ chain_targets,
    float* __restrict__ ws,       // NBLK*3 floats, then 1 uint counter
    float* __restrict__ out)
{
    const int nb = blockIdx.x;        // 0..15
    const int n = nb / BB;
    const int b = nb % BB;
    const int tid = threadIdx.x;

    __shared__ unsigned bitmap[VWORDS];   // 6284 B
    __shared__ int toks[LL];              // unique token ids (K <= 256)
    __shared__ unsigned ucnt;
    __shared__ float sm[TPB];
    __shared__ float ss[TPB];
    __shared__ int   si[TPB];

    // Zero bitmap + counter
    for (int i = tid; i < VWORDS; i += TPB) bitmap[i] = 0u;
    if (tid == 0) ucnt = 0u;
    __syncthreads();

    // Dedupe-compact: first thread to set a token's bit owns it
    {
        int t = input_ids[b * LL + tid];           // LL == TPB == 256
        unsigned bit = 1u << (t & 31);
        unsigned old = atomicOr(&bitmap[t >> 5], bit);
        if (!(old & bit)) {
            unsigned p = atomicAdd(&ucnt, 1u);
            toks[p] = t;
        }
    }
    __syncthreads();
    const int K = (int)ucnt;                       // >= 1 always

    const int as = ans_starts[b];
    const bool pos_ok = (as >= 1) && (as < LL);
    int as_idx = as - 1;
    if (as_idx < 0) as_idx = 0;
    if (as_idx > LL - 1) as_idx = LL - 1;

    const float* row = logits + (((size_t)n * BB + b) * LL + as_idx) * (size_t)VV;

    // Gather my valid logit (scattered; inherently uncoalesced, ~1 line each)
    float x = -INFINITY;
    int   idx = 0x7fffffff;
    if (tid < K) {
        idx = toks[tid];
        x = row[idx];
    }

    // Pass 1: max + first-argmax (lowest token id on ties — matches jnp.argmax)
    sm[tid] = x; si[tid] = idx;
    __syncthreads();
    for (int off = TPB / 2; off > 0; off >>= 1) {
        if (tid < off) {
            float m1 = sm[tid], m2 = sm[tid + off];
            int   i1 = si[tid], i2 = si[tid + off];
            if (m2 > m1 || (m2 == m1 && i2 < i1)) { sm[tid] = m2; si[tid] = i2; }
        }
        __syncthreads();
    }
    const float m = sm[0];
    const int pred = si[0];
    __syncthreads();

    // Pass 2: sum of exp(x - m) over valid tokens
    ss[tid] = (tid < K) ? expf(x - m) : 0.0f;
    __syncthreads();
    for (int off = TPB / 2; off > 0; off >>= 1) {
        if (tid < off) ss[tid] += ss[tid + off];
        __syncthreads();
    }

    if (tid == 0) {
        const int tgt = chain_targets[b * NL + n];   // chain_targets.T[n][b]
        const bool tgt_ok = ((bitmap[tgt >> 5] >> (tgt & 31)) & 1u) != 0u;
        const bool valid = pos_ok && tgt_ok;

        float ce = 0.0f, ac = 0.0f, vf = 0.0f;
        if (valid) {
            vf = 1.0f;
            float lt = row[tgt];                     // masked[tgt] == la[tgt] when tgt_ok
            ce = -(lt - m - logf(ss[0]));
            ac = (pred == tgt) ? 1.0f : 0.0f;
        }
        float* w = ws + (size_t)nb * 3;
        w[0] = ce; w[1] = ac; w[2] = vf;

        // Release: make ws visible device-wide, then count in.
        __threadfence();
        unsigned prev = atomicAdd((unsigned*)(ws + NBLK * 3), 1u);
        if (prev == NBLK - 1) {
            // Acquire: all 16 blocks' ws writes are now visible.
            __threadfence();
            volatile const float* vws = (volatile const float*)ws;
            float loss_num = 0.0f, acc_num = 0.0f, has_sum = 0.0f, final_acc = 0.0f;
            for (int nn = 0; nn < NL; ++nn) {
                float ces = 0.0f, acs = 0.0f, cnt = 0.0f;
                for (int bb = 0; bb < BB; ++bb) {
                    const int base = (nn * BB + bb) * 3;
                    ces += vws[base + 0];
                    acs += vws[base + 1];
                    cnt += vws[base + 2];
                }
                float denom = fmaxf(cnt, 1.0f);
                float ll = ces / denom;
                float la = acs / denom;
                float has = (cnt > 0.0f) ? 1.0f : 0.0f;
                loss_num += ll * has;
                acc_num  += la * has;
                has_sum  += has;
                if (nn == NL - 1) final_acc = la;
            }
            float nv = fmaxf(has_sum, 1.0f);
            out[0] = loss_num / nv;
            out[1] = acc_num / nv;
            out[2] = final_acc;
        }
    }
}

extern "C" void kernel_launch(void* const* d_in, const int* in_sizes, int n_in,
                              void* d_out, int out_size, void* d_ws, size_t ws_size,
                              hipStream_t stream) {
    const float* logits        = (const float*)d_in[0];
    const int*   input_ids     = (const int*)d_in[1];
    const int*   ans_starts    = (const int*)d_in[2];
    const int*   chain_targets = (const int*)d_in[3];
    float* out = (float*)d_out;
    float* ws  = (float*)d_ws;

    // Zero the arrival counter each replay (graph-capture-safe memset node).
    hipMemsetAsync(ws + NBLK * 3, 0, sizeof(unsigned), stream);

    fused_metric_kernel<<<dim3(NBLK), dim3(TPB), 0, stream>>>(
        logits, input_ids, ans_starts, chain_targets, ws, out);
}